// Round 1
// baseline (1053.153 us; speedup 1.0000x reference)
//
#include <hip/hip_runtime.h>

// GraphFilter: B=16,T=64,Fin=Fout=64,N=128,E=2,K=4
// y[b,t,o,n] = bias[o] + sum_{e,k,f} H[o,e,k,f] * tap_k[b,t,e,f,n]
// tap_0 = x (bcast over e); tap_k[b,t,e] = tap_{k-1}[b,t-1,e] @ S[b,t,e]
//
// Restructured (projection-first Horner):
//   U_k[b,s,e][o][n] = sum_f H[o,e,k,f] x[b,s,f,n]
//   W2[b,s,e] = U_2[b,s,e] + U_3[b,s-1,e] @ S[b,s,e]
//   W1[b,s,e] = U_1[b,s,e] + W2[b,s-1,e] @ S[b,s,e]
//   y[b,t]    = bias + sum_e ( U_0[b,t,e] + W1[b,t-1,e] @ S[b,t,e] )

namespace {
constexpr int B = 16, T = 64, FIN = 64, FOUT = 64, NV = 128, E = 2, K = 4;
}

// One block per (b,s,e-slot). Computes:
//   Out[b,s,le][o][n] = sum_f H[o,e,ktap,f]*x[b,s,f,n]
//                     + (Pin && s>0 ? sum_m Pin[b,s-1,le][o][m]*S[b,s,e][m][n] : 0)
__global__ __launch_bounds__(256) void gf_step(
    const float* __restrict__ x, const float* __restrict__ S,
    const float* __restrict__ H, const float* __restrict__ Pin,
    float* __restrict__ Out, int ktap, int e_base, int e_count)
{
  __shared__ float Hs[FOUT * FIN];   // 16 KB
  __shared__ float Ps[FOUT * NV];    // 32 KB
  __shared__ float Ss[32 * NV];      // 16 KB   (total 64 KB -> 2 blocks/CU)

  const int bid = blockIdx.x;
  const int le  = bid % e_count;
  const int e   = e_base + le;
  const int s   = (bid / e_count) % T;
  const int b   = bid / (e_count * T);
  const int tid = threadIdx.x;
  const int tx = tid & 31, ty = tid >> 5;
  const int n0 = tx * 4, o0 = ty * 8;   // 8o x 4n register tile

  // Stage H[:,e,ktap,:]
  for (int i = tid; i < FOUT * FIN; i += 256) {
    const int o = i >> 6, f = i & 63;
    Hs[i] = H[((o * E + e) * K + ktap) * FIN + f];
  }
  const bool has_p = (Pin != nullptr) && (s > 0);
  if (has_p) {
    const float4* Pg = (const float4*)(Pin +
        (size_t)((b * T + (s - 1)) * e_count + le) * FOUT * NV);
    float4* Pd = (float4*)Ps;
    for (int i = tid; i < FOUT * NV / 4; i += 256) Pd[i] = Pg[i];
  }
  __syncthreads();

  float acc[8][4];
  #pragma unroll
  for (int i = 0; i < 8; ++i) { acc[i][0]=0.f; acc[i][1]=0.f; acc[i][2]=0.f; acc[i][3]=0.f; }

  // Projection: acc[o][n] += H[o][f] * x[b,s,f,n]  (x read from global, coalesced float4)
  {
    const float* xp = x + (size_t)(b * T + s) * FIN * NV + n0;
    for (int f = 0; f < FIN; f += 4) {
      const float4 xv0 = *(const float4*)(xp + (f + 0) * NV);
      const float4 xv1 = *(const float4*)(xp + (f + 1) * NV);
      const float4 xv2 = *(const float4*)(xp + (f + 2) * NV);
      const float4 xv3 = *(const float4*)(xp + (f + 3) * NV);
      #pragma unroll
      for (int i = 0; i < 8; ++i) {
        const float4 hv = *(const float4*)(&Hs[(o0 + i) * FIN + f]);
        acc[i][0] += hv.x*xv0.x + hv.y*xv1.x + hv.z*xv2.x + hv.w*xv3.x;
        acc[i][1] += hv.x*xv0.y + hv.y*xv1.y + hv.z*xv2.y + hv.w*xv3.y;
        acc[i][2] += hv.x*xv0.z + hv.y*xv1.z + hv.z*xv2.z + hv.w*xv3.z;
        acc[i][3] += hv.x*xv0.w + hv.y*xv1.w + hv.z*xv2.w + hv.w*xv3.w;
      }
    }
  }

  if (has_p) {
    const float* Sp = S + (size_t)((b * T + s) * E + e) * NV * NV;
    for (int c = 0; c < NV; c += 32) {
      __syncthreads();
      const float4* Sg = (const float4*)(Sp + c * NV);
      float4* Sd = (float4*)Ss;
      for (int i = tid; i < 32 * NV / 4; i += 256) Sd[i] = Sg[i];
      __syncthreads();
      #pragma unroll
      for (int mm = 0; mm < 32; mm += 4) {
        const float4 sv0 = *(const float4*)(&Ss[(mm + 0) * NV + n0]);
        const float4 sv1 = *(const float4*)(&Ss[(mm + 1) * NV + n0]);
        const float4 sv2 = *(const float4*)(&Ss[(mm + 2) * NV + n0]);
        const float4 sv3 = *(const float4*)(&Ss[(mm + 3) * NV + n0]);
        #pragma unroll
        for (int i = 0; i < 8; ++i) {
          const float4 pv = *(const float4*)(&Ps[(o0 + i) * NV + c + mm]);
          acc[i][0] += pv.x*sv0.x + pv.y*sv1.x + pv.z*sv2.x + pv.w*sv3.x;
          acc[i][1] += pv.x*sv0.y + pv.y*sv1.y + pv.z*sv2.y + pv.w*sv3.y;
          acc[i][2] += pv.x*sv0.z + pv.y*sv1.z + pv.z*sv2.z + pv.w*sv3.z;
          acc[i][3] += pv.x*sv0.w + pv.y*sv1.w + pv.z*sv2.w + pv.w*sv3.w;
        }
      }
    }
  }

  float* op = Out + (size_t)((b * T + s) * e_count + le) * FOUT * NV + n0;
  #pragma unroll
  for (int i = 0; i < 8; ++i)
    *(float4*)(op + (o0 + i) * NV) =
        make_float4(acc[i][0], acc[i][1], acc[i][2], acc[i][3]);
}

// One block per (b,t). y[b,t][o][n] = (first_pass ? bias[o] : y[..]) +
//   sum_{le} ( U_0 + (t>0 ? W1[b,t-1,le] @ S[b,t,e] : 0) )
__global__ __launch_bounds__(256) void gf_final(
    const float* __restrict__ x, const float* __restrict__ S,
    const float* __restrict__ H, const float* __restrict__ bias,
    const float* __restrict__ Pin, float* __restrict__ y,
    int e_base, int e_count, int first_pass)
{
  __shared__ float Hs[FOUT * FIN];
  __shared__ float Ps[FOUT * NV];
  __shared__ float Ss[32 * NV];

  const int bid = blockIdx.x;
  const int t = bid % T;
  const int b = bid / T;
  const int tid = threadIdx.x;
  const int tx = tid & 31, ty = tid >> 5;
  const int n0 = tx * 4, o0 = ty * 8;

  float acc[8][4];
  #pragma unroll
  for (int i = 0; i < 8; ++i) { acc[i][0]=0.f; acc[i][1]=0.f; acc[i][2]=0.f; acc[i][3]=0.f; }

  const bool has_p = (t > 0);

  for (int le = 0; le < e_count; ++le) {
    const int e = e_base + le;
    __syncthreads();  // protect Hs/Ps from previous iteration's readers
    for (int i = tid; i < FOUT * FIN; i += 256) {
      const int o = i >> 6, f = i & 63;
      Hs[i] = H[((o * E + e) * K + 0) * FIN + f];
    }
    if (has_p) {
      const float4* Pg = (const float4*)(Pin +
          (size_t)((b * T + (t - 1)) * e_count + le) * FOUT * NV);
      float4* Pd = (float4*)Ps;
      for (int i = tid; i < FOUT * NV / 4; i += 256) Pd[i] = Pg[i];
    }
    __syncthreads();

    // Projection U_0
    {
      const float* xp = x + (size_t)(b * T + t) * FIN * NV + n0;
      for (int f = 0; f < FIN; f += 4) {
        const float4 xv0 = *(const float4*)(xp + (f + 0) * NV);
        const float4 xv1 = *(const float4*)(xp + (f + 1) * NV);
        const float4 xv2 = *(const float4*)(xp + (f + 2) * NV);
        const float4 xv3 = *(const float4*)(xp + (f + 3) * NV);
        #pragma unroll
        for (int i = 0; i < 8; ++i) {
          const float4 hv = *(const float4*)(&Hs[(o0 + i) * FIN + f]);
          acc[i][0] += hv.x*xv0.x + hv.y*xv1.x + hv.z*xv2.x + hv.w*xv3.x;
          acc[i][1] += hv.x*xv0.y + hv.y*xv1.y + hv.z*xv2.y + hv.w*xv3.y;
          acc[i][2] += hv.x*xv0.z + hv.y*xv1.z + hv.z*xv2.z + hv.w*xv3.z;
          acc[i][3] += hv.x*xv0.w + hv.y*xv1.w + hv.z*xv2.w + hv.w*xv3.w;
        }
      }
    }

    if (has_p) {
      const float* Sp = S + (size_t)((b * T + t) * E + e) * NV * NV;
      for (int c = 0; c < NV; c += 32) {
        __syncthreads();
        const float4* Sg = (const float4*)(Sp + c * NV);
        float4* Sd = (float4*)Ss;
        for (int i = tid; i < 32 * NV / 4; i += 256) Sd[i] = Sg[i];
        __syncthreads();
        #pragma unroll
        for (int mm = 0; mm < 32; mm += 4) {
          const float4 sv0 = *(const float4*)(&Ss[(mm + 0) * NV + n0]);
          const float4 sv1 = *(const float4*)(&Ss[(mm + 1) * NV + n0]);
          const float4 sv2 = *(const float4*)(&Ss[(mm + 2) * NV + n0]);
          const float4 sv3 = *(const float4*)(&Ss[(mm + 3) * NV + n0]);
          #pragma unroll
          for (int i = 0; i < 8; ++i) {
            const float4 pv = *(const float4*)(&Ps[(o0 + i) * NV + c + mm]);
            acc[i][0] += pv.x*sv0.x + pv.y*sv1.x + pv.z*sv2.x + pv.w*sv3.x;
            acc[i][1] += pv.x*sv0.y + pv.y*sv1.y + pv.z*sv2.y + pv.w*sv3.y;
            acc[i][2] += pv.x*sv0.z + pv.y*sv1.z + pv.z*sv2.z + pv.w*sv3.z;
            acc[i][3] += pv.x*sv0.w + pv.y*sv1.w + pv.z*sv2.w + pv.w*sv3.w;
          }
        }
      }
    }
  }

  float* yp = y + (size_t)(b * T + t) * FOUT * NV + n0;
  #pragma unroll
  for (int i = 0; i < 8; ++i) {
    float4 v = make_float4(acc[i][0], acc[i][1], acc[i][2], acc[i][3]);
    float* row = yp + (o0 + i) * NV;
    if (first_pass) {
      const float bv = bias[o0 + i];
      v.x += bv; v.y += bv; v.z += bv; v.w += bv;
    } else {
      const float4 old = *(const float4*)row;
      v.x += old.x; v.y += old.y; v.z += old.z; v.w += old.w;
    }
    *(float4*)row = v;
  }
}

extern "C" void kernel_launch(void* const* d_in, const int* in_sizes, int n_in,
                              void* d_out, int out_size, void* d_ws, size_t ws_size,
                              hipStream_t stream) {
  const float* x    = (const float*)d_in[0];
  const float* S    = (const float*)d_in[1];
  const float* H    = (const float*)d_in[2];
  const float* bias = (const float*)d_in[3];
  float* y = (float*)d_out;

  const size_t per_e = (size_t)B * T * FOUT * NV;  // 8,388,608 floats (32 MB)

  if (ws_size >= 2 * per_e * E * sizeof(float)) {
    // Primary path: both e in flight; ws = 2 x 64 MB ping-pong.
    float* bufA = (float*)d_ws;
    float* bufB = bufA + per_e * E;
    gf_step<<<B * T * E, 256, 0, stream>>>(x, S, H, nullptr, bufA, 3, 0, E);
    gf_step<<<B * T * E, 256, 0, stream>>>(x, S, H, bufA,    bufB, 2, 0, E);
    gf_step<<<B * T * E, 256, 0, stream>>>(x, S, H, bufB,    bufA, 1, 0, E);
    gf_final<<<B * T, 256, 0, stream>>>(x, S, H, bias, bufA, y, 0, E, 1);
  } else {
    // Fallback: sequential over e; ws = 2 x 32 MB.
    float* bufA = (float*)d_ws;
    float* bufB = bufA + per_e;
    for (int e = 0; e < E; ++e) {
      gf_step<<<B * T, 256, 0, stream>>>(x, S, H, nullptr, bufA, 3, e, 1);
      gf_step<<<B * T, 256, 0, stream>>>(x, S, H, bufA,    bufB, 2, e, 1);
      gf_step<<<B * T, 256, 0, stream>>>(x, S, H, bufB,    bufA, 1, e, 1);
      gf_final<<<B * T, 256, 0, stream>>>(x, S, H, bias, bufA, y, e, 1, e == 0);
    }
  }
}

// Round 2
// 321.608 us; speedup vs baseline: 3.2746x; 3.2746x over previous
//
#include <hip/hip_runtime.h>

// GraphFilter B=16,T=64,F=64,N=128,E=2,K=4 — bf16 MFMA pipeline.
// y[t] = bias + sum_e [ U0[t] + W1[t-1]@S[t] ]
//   W1[s] = U1[s] + W2[s-1]@S[s]
//   W2[s] = U2[s] + U3[s-1]@S[s]     (U3 computed in-kernel, LDS round-trip)
//   U_k[s][o][n] = sum_f H[o,e,k,f] x[s,f,n]
// MFMA 16x16x32 bf16: A[m=lane&15][k=quad*8+j], B[n=lane&15][k=quad*8+j],
// C/D col=lane&15, row=quad*4+reg.  S stored pre-transposed bf16 [n][m].

namespace {
constexpr int B = 16, T = 64, F = 64, N = 128, E = 2, K = 4;
constexpr int SH = 72;   // sH stride  [64][72]
constexpr int SX = 72;   // sB stride  [128][72] (xT tile or S^T half tile)
constexpr int SA = 136;  // sA stride  [64][136] (A-operand: Pin or U3)
}

typedef short v8s __attribute__((ext_vector_type(8)));
typedef float v4f __attribute__((ext_vector_type(4)));

__device__ inline ushort f2bf(float f) {
  union { float f; uint u; } v; v.f = f;
  uint u = v.u;
  return (ushort)((u + 0x7fffu + ((u >> 16) & 1u)) >> 16);
}

__device__ inline uint4 pack8(const ushort* p) {
  uint4 w;
  w.x = (uint)p[0] | ((uint)p[1] << 16);
  w.y = (uint)p[2] | ((uint)p[3] << 16);
  w.z = (uint)p[4] | ((uint)p[5] << 16);
  w.w = (uint)p[6] | ((uint)p[7] << 16);
  return w;
}

// ---------------- S transpose+convert: fp32 [m][n] -> bf16 [n][m] ----------
__global__ __launch_bounds__(256) void cvt_S(const float* __restrict__ S,
                                             ushort* __restrict__ ST,
                                             int e_base, int e_count) {
  __shared__ ushort tile[128 * 130];
  const int bid = blockIdx.x;
  const int le = bid % e_count, s = (bid / e_count) % T, b = bid / (e_count * T);
  const int e = e_base + le;
  const float* Sg = S + (size_t)((b * T + s) * E + e) * N * N;
  ushort* Og = ST + (size_t)((b * T + s) * e_count + le) * N * N;
  const int tid = threadIdx.x;
  #pragma unroll
  for (int it = 0; it < 16; ++it) {
    const int idx = tid + it * 256;
    const int m = idx >> 5, n4 = (idx & 31) * 4;
    const float4 v = *(const float4*)(Sg + m * N + n4);
    uint* lp = (uint*)&tile[m * 130 + n4];
    lp[0] = (uint)f2bf(v.x) | ((uint)f2bf(v.y) << 16);
    lp[1] = (uint)f2bf(v.z) | ((uint)f2bf(v.w) << 16);
  }
  __syncthreads();
  #pragma unroll
  for (int it = 0; it < 4; ++it) {
    const int idx = tid + it * 256;          // 0..1023
    const int m8 = (idx & 15) * 8, n2 = idx >> 4;
    uint r[8];
    #pragma unroll
    for (int j = 0; j < 8; ++j)
      r[j] = *(const uint*)&tile[(m8 + j) * 130 + 2 * n2];
    uint4 w0, w1;
    w0.x = (r[0] & 0xffffu) | (r[1] << 16);
    w0.y = (r[2] & 0xffffu) | (r[3] << 16);
    w0.z = (r[4] & 0xffffu) | (r[5] << 16);
    w0.w = (r[6] & 0xffffu) | (r[7] << 16);
    w1.x = (r[0] >> 16) | (r[1] & 0xffff0000u);
    w1.y = (r[2] >> 16) | (r[3] & 0xffff0000u);
    w1.z = (r[4] >> 16) | (r[5] & 0xffff0000u);
    w1.w = (r[6] >> 16) | (r[7] & 0xffff0000u);
    *(uint4*)(Og + (2 * n2) * N + m8) = w0;
    *(uint4*)(Og + (2 * n2 + 1) * N + m8) = w1;
  }
}

// ---------------- staging helpers ----------------
__device__ inline void stage_H(const float* __restrict__ Hg, int e, int k,
                               ushort* sH, int tid) {
  #pragma unroll
  for (int it = 0; it < 2; ++it) {
    const int idx = tid + it * 256;          // 0..511
    const int o = idx & 63, f8 = (idx >> 6) * 8;
    const float* src = Hg + ((size_t)(o * E + e) * K + k) * F + f8;
    ushort p[8];
    #pragma unroll
    for (int j = 0; j < 8; ++j) p[j] = f2bf(src[j]);
    *(uint4*)&sH[o * SH + f8] = pack8(p);
  }
}

// transpose-convert x[b,s] fp32 [f][n] -> sX bf16 [n][f]
__device__ inline void stage_X(const float* __restrict__ xg, ushort* sX, int tid) {
  #pragma unroll
  for (int it = 0; it < 4; ++it) {
    const int idx = tid + it * 256;          // 0..1023
    const int n = idx & 127, f8 = (idx >> 7) * 8;
    ushort p[8];
    #pragma unroll
    for (int j = 0; j < 8; ++j) p[j] = f2bf(xg[(f8 + j) * N + n]);
    *(uint4*)&sX[n * SX + f8] = pack8(p);
  }
}

__device__ inline void stage_A(const ushort* __restrict__ Pg, ushort* sA, int tid) {
  #pragma unroll
  for (int it = 0; it < 4; ++it) {
    const int idx = tid + it * 256;          // 0..1023
    const int o = idx >> 4, m8 = (idx & 15) * 8;
    *(uint4*)&sA[o * SA + m8] = *(const uint4*)(Pg + o * N + m8);
  }
}

__device__ inline void stage_Sh(const ushort* __restrict__ STg, int h,
                                ushort* sB, int tid) {
  #pragma unroll
  for (int it = 0; it < 4; ++it) {
    const int idx = tid + it * 256;          // 0..1023
    const int n = idx >> 3, m8 = (idx & 7) * 8;
    *(uint4*)&sB[n * SX + m8] = *(const uint4*)(STg + n * N + h * 64 + m8);
  }
}

// ---------------- MFMA tiles ----------------
__device__ inline void zero_acc(v4f acc[2][4]) {
  #pragma unroll
  for (int i = 0; i < 2; ++i)
    #pragma unroll
    for (int j = 0; j < 4; ++j) {
      acc[i][j][0] = 0.f; acc[i][j][1] = 0.f; acc[i][j][2] = 0.f; acc[i][j][3] = 0.f;
    }
}

__device__ inline void do_proj(const ushort* sH, const ushort* sX, v4f acc[2][4],
                               int ob0, int nb0, int l15, int q) {
  #pragma unroll
  for (int fk = 0; fk < 2; ++fk) {
    v8s a[2], bb[4];
    #pragma unroll
    for (int mt = 0; mt < 2; ++mt)
      a[mt] = *(const v8s*)&sH[(ob0 + 16 * mt + l15) * SH + fk * 32 + q * 8];
    #pragma unroll
    for (int nt = 0; nt < 4; ++nt)
      bb[nt] = *(const v8s*)&sX[(nb0 + 16 * nt + l15) * SX + fk * 32 + q * 8];
    #pragma unroll
    for (int mt = 0; mt < 2; ++mt)
      #pragma unroll
      for (int nt = 0; nt < 4; ++nt)
        acc[mt][nt] = __builtin_amdgcn_mfma_f32_16x16x32_bf16(
            a[mt], bb[nt], acc[mt][nt], 0, 0, 0);
  }
}

__device__ inline void do_mm(const ushort* sA, const ushort* sB, int h,
                             v4f acc[2][4], int ob0, int nb0, int l15, int q) {
  #pragma unroll
  for (int lk = 0; lk < 2; ++lk) {
    v8s a[2], bb[4];
    #pragma unroll
    for (int mt = 0; mt < 2; ++mt)
      a[mt] = *(const v8s*)&sA[(ob0 + 16 * mt + l15) * SA + h * 64 + lk * 32 + q * 8];
    #pragma unroll
    for (int nt = 0; nt < 4; ++nt)
      bb[nt] = *(const v8s*)&sB[(nb0 + 16 * nt + l15) * SX + lk * 32 + q * 8];
    #pragma unroll
    for (int mt = 0; mt < 2; ++mt)
      #pragma unroll
      for (int nt = 0; nt < 4; ++nt)
        acc[mt][nt] = __builtin_amdgcn_mfma_f32_16x16x32_bf16(
            a[mt], bb[nt], acc[mt][nt], 0, 0, 0);
  }
}

__device__ inline void store_W(ushort* __restrict__ Wg, v4f acc[2][4],
                               int ob0, int nb0, int l15, int q) {
  #pragma unroll
  for (int mt = 0; mt < 2; ++mt)
    #pragma unroll
    for (int nt = 0; nt < 4; ++nt) {
      const int col = nb0 + 16 * nt + l15;
      #pragma unroll
      for (int r = 0; r < 4; ++r)
        Wg[(ob0 + 16 * mt + q * 4 + r) * N + col] = f2bf(acc[mt][nt][r]);
    }
}

__device__ inline void store_sA(ushort* sA, v4f acc[2][4],
                                int ob0, int nb0, int l15, int q) {
  #pragma unroll
  for (int mt = 0; mt < 2; ++mt)
    #pragma unroll
    for (int nt = 0; nt < 4; ++nt) {
      const int col = nb0 + 16 * nt + l15;
      #pragma unroll
      for (int r = 0; r < 4; ++r)
        sA[(ob0 + 16 * mt + q * 4 + r) * SA + col] = f2bf(acc[mt][nt][r]);
    }
}

// ---------------- pass 2: W2 = U2 + U3[s-1]@S[s] (U3 fused) ----------------
__global__ __launch_bounds__(256) void gf_p2(
    const float* __restrict__ x, const ushort* __restrict__ ST,
    const float* __restrict__ H, ushort* __restrict__ Out,
    int e_base, int e_count) {
  __shared__ ushort sH[64 * SH];
  __shared__ ushort sB[128 * SX];
  __shared__ ushort sA[64 * SA];
  const int bid = blockIdx.x;
  const int le = bid % e_count, s = (bid / e_count) % T, b = bid / (e_count * T);
  const int e = e_base + le;
  const int tid = threadIdx.x, w = tid >> 6, lane = tid & 63;
  const int l15 = lane & 15, q = lane >> 4;
  const int ob0 = (w & 1) * 32, nb0 = (w >> 1) * 64;
  const bool has_p = (s > 0);
  const ushort* STg = ST + (size_t)((b * T + s) * e_count + le) * N * N;
  v4f acc[2][4];
  zero_acc(acc);
  if (has_p) {
    stage_H(H, e, 3, sH, tid);
    stage_X(x + (size_t)(b * T + s - 1) * F * N, sB, tid);
    __syncthreads();
    do_proj(sH, sB, acc, ob0, nb0, l15, q);      // U3[s-1]
    __syncthreads();
    store_sA(sA, acc, ob0, nb0, l15, q);         // U3 -> A-operand layout
    zero_acc(acc);
  }
  stage_H(H, e, 2, sH, tid);
  stage_X(x + (size_t)(b * T + s) * F * N, sB, tid);
  __syncthreads();
  do_proj(sH, sB, acc, ob0, nb0, l15, q);        // U2[s]
  if (has_p) {
    #pragma unroll
    for (int h = 0; h < 2; ++h) {
      __syncthreads();
      stage_Sh(STg, h, sB, tid);
      __syncthreads();
      do_mm(sA, sB, h, acc, ob0, nb0, l15, q);
    }
  }
  store_W(Out + (size_t)((b * T + s) * e_count + le) * F * N, acc, ob0, nb0, l15, q);
}

// ---------------- pass 1: W1 = U1 + W2[s-1]@S[s] ----------------
__global__ __launch_bounds__(256) void gf_p1(
    const float* __restrict__ x, const ushort* __restrict__ ST,
    const float* __restrict__ H, const ushort* __restrict__ Pin,
    ushort* __restrict__ Out, int ktap, int e_base, int e_count) {
  __shared__ ushort sH[64 * SH];
  __shared__ ushort sB[128 * SX];
  __shared__ ushort sA[64 * SA];
  const int bid = blockIdx.x;
  const int le = bid % e_count, s = (bid / e_count) % T, b = bid / (e_count * T);
  const int e = e_base + le;
  const int tid = threadIdx.x, w = tid >> 6, lane = tid & 63;
  const int l15 = lane & 15, q = lane >> 4;
  const int ob0 = (w & 1) * 32, nb0 = (w >> 1) * 64;
  const bool has_p = (s > 0);
  const ushort* STg = ST + (size_t)((b * T + s) * e_count + le) * N * N;
  v4f acc[2][4];
  zero_acc(acc);
  stage_H(H, e, ktap, sH, tid);
  stage_X(x + (size_t)(b * T + s) * F * N, sB, tid);
  if (has_p)
    stage_A(Pin + (size_t)((b * T + s - 1) * e_count + le) * F * N, sA, tid);
  __syncthreads();
  do_proj(sH, sB, acc, ob0, nb0, l15, q);
  if (has_p) {
    #pragma unroll
    for (int h = 0; h < 2; ++h) {
      __syncthreads();
      stage_Sh(STg, h, sB, tid);
      __syncthreads();
      do_mm(sA, sB, h, acc, ob0, nb0, l15, q);
    }
  }
  store_W(Out + (size_t)((b * T + s) * e_count + le) * F * N, acc, ob0, nb0, l15, q);
}

// ---------------- final: y = bias + sum_e (U0 + W1[t-1]@S[t]) ----------------
__global__ __launch_bounds__(256) void gf_final(
    const float* __restrict__ x, const ushort* __restrict__ ST,
    const float* __restrict__ H, const float* __restrict__ bias,
    const ushort* __restrict__ Pin, float* __restrict__ y,
    int e_base, int e_count, int first_pass) {
  __shared__ ushort sH[64 * SH];
  __shared__ ushort sB[128 * SX];
  __shared__ ushort sA[64 * SA];
  const int bid = blockIdx.x;
  const int t = bid % T, b = bid / T;
  const int tid = threadIdx.x, w = tid >> 6, lane = tid & 63;
  const int l15 = lane & 15, q = lane >> 4;
  const int ob0 = (w & 1) * 32, nb0 = (w >> 1) * 64;
  const bool has_p = (t > 0);
  v4f acc[2][4];
  zero_acc(acc);
  for (int le = 0; le < e_count; ++le) {
    const int e = e_base + le;
    __syncthreads();  // protect LDS from previous iteration's readers
    stage_H(H, e, 0, sH, tid);
    stage_X(x + (size_t)(b * T + t) * F * N, sB, tid);
    if (has_p)
      stage_A(Pin + (size_t)((b * T + t - 1) * e_count + le) * F * N, sA, tid);
    __syncthreads();
    do_proj(sH, sB, acc, ob0, nb0, l15, q);      // U0
    if (has_p) {
      const ushort* STg = ST + (size_t)((b * T + t) * e_count + le) * N * N;
      #pragma unroll
      for (int h = 0; h < 2; ++h) {
        __syncthreads();
        stage_Sh(STg, h, sB, tid);
        __syncthreads();
        do_mm(sA, sB, h, acc, ob0, nb0, l15, q);
      }
    }
  }
  float* yg = y + (size_t)(b * T + t) * F * N;
  #pragma unroll
  for (int mt = 0; mt < 2; ++mt)
    #pragma unroll
    for (int nt = 0; nt < 4; ++nt) {
      const int col = nb0 + 16 * nt + l15;
      #pragma unroll
      for (int r = 0; r < 4; ++r) {
        const int row = ob0 + 16 * mt + q * 4 + r;
        float v = acc[mt][nt][r];
        v += first_pass ? bias[row] : yg[row * N + col];
        yg[row * N + col] = v;
      }
    }
}

extern "C" void kernel_launch(void* const* d_in, const int* in_sizes, int n_in,
                              void* d_out, int out_size, void* d_ws, size_t ws_size,
                              hipStream_t stream) {
  const float* x    = (const float*)d_in[0];
  const float* S    = (const float*)d_in[1];
  const float* H    = (const float*)d_in[2];
  const float* bias = (const float*)d_in[3];
  float* y = (float*)d_out;

  const size_t ST2 = (size_t)B * T * 2 * N * N;   // 33,554,432 ushorts
  const size_t W2e = (size_t)B * T * 2 * F * N;   // 16,777,216 ushorts
  const size_t need2 = (ST2 + 2 * W2e) * sizeof(ushort);  // 128 MB

  if (ws_size >= need2) {
    ushort* ST   = (ushort*)d_ws;
    ushort* bufA = ST + ST2;      // W2
    ushort* bufB = bufA + W2e;    // W1
    cvt_S   <<<B * T * 2, 256, 0, stream>>>(S, ST, 0, 2);
    gf_p2   <<<B * T * 2, 256, 0, stream>>>(x, ST, H, bufA, 0, 2);
    gf_p1   <<<B * T * 2, 256, 0, stream>>>(x, ST, H, bufA, bufB, 1, 0, 2);
    gf_final<<<B * T,     256, 0, stream>>>(x, ST, H, bias, bufB, y, 0, 2, 1);
  } else {
    // per-e fallback: 64 MB workspace
    const size_t ST1 = (size_t)B * T * N * N;     // 16,777,216
    const size_t W1e = (size_t)B * T * F * N;     // 8,388,608
    ushort* ST   = (ushort*)d_ws;
    ushort* bufA = ST + ST1;
    ushort* bufB = bufA + W1e;
    for (int e = 0; e < E; ++e) {
      cvt_S   <<<B * T, 256, 0, stream>>>(S, ST, e, 1);
      gf_p2   <<<B * T, 256, 0, stream>>>(x, ST, H, bufA, e, 1);
      gf_p1   <<<B * T, 256, 0, stream>>>(x, ST, H, bufA, bufB, 1, e, 1);
      gf_final<<<B * T, 256, 0, stream>>>(x, ST, H, bias, bufB, y, e, 1, e == 0);
    }
  }
}